// Round 2
// baseline (124.185 us; speedup 1.0000x reference)
//
#include <hip/hip_runtime.h>

// Problem constants (from reference): B=4, C=5, H=64, W=64, N=4096
#define Bq  4
#define Cc  5
#define Hh  64
#define Ww  64
#define HW  (Hh * Ww)       // 4096
#define CHW (Cc * HW)       // 20480
#define HW4 (HW / 4)        // 1024 float4 per plane
#define NQMAX (Bq * HW4)    // 4096 threads in prep == max bucketable queries
#define Gq  4               // queries per wave in grouped attention

__device__ __forceinline__ float fast_exp2(float x) {
#if __has_builtin(__builtin_amdgcn_exp2f)
    return __builtin_amdgcn_exp2f(x);
#else
    return exp2f(x);
#endif
}

// ---------------------------------------------------------------------------
// Kernel A: K/V precompute (float4) + fused y=x copy + deterministic batch
// bucketing. 4096 threads = 64 waves; wave W compacts its 64 queries into
// per-(segment,batch) lists via ballot/popcount — no atomics, no memset.
// ---------------------------------------------------------------------------
__global__ __launch_bounds__(256) void prep_f4(
    const float4* __restrict__ x4,
    const float* __restrict__ kw, const float* __restrict__ kb,
    const float* __restrict__ vw, const float* __restrict__ vb,
    const int* __restrict__ idx_b, int N,
    float4* __restrict__ K4, float4* __restrict__ V4, float4* __restrict__ y4,
    int* __restrict__ seg_bkt,   // [Bq][64 segs][64]  = Bq*NQMAX ints
    int* __restrict__ seg_cnt)   // [Bq][64 segs]
{
    int t = blockIdx.x * blockDim.x + threadIdx.x;   // 0..4095
    if (t >= NQMAX) return;

    // ---- K/V + y=x copy ----
    {
        int b = t >> 10;            // / HW4
        int p = t & (HW4 - 1);      // % HW4
        const int base = b * (Cc * HW4);
        float4 xi[Cc];
#pragma unroll
        for (int c = 0; c < Cc; ++c) {
            xi[c] = x4[base + c * HW4 + p];
            y4[base + c * HW4 + p] = xi[c];     // fused y = x copy
        }
#pragma unroll
        for (int o = 0; o < Cc; ++o) {
            float kbo = kb[o], vbo = vb[o];
            float4 ka = {kbo, kbo, kbo, kbo};
            float4 va = {vbo, vbo, vbo, vbo};
#pragma unroll
            for (int c = 0; c < Cc; ++c) {
                float kwv = kw[o * Cc + c];
                float vwv = vw[o * Cc + c];
                ka.x += kwv * xi[c].x; ka.y += kwv * xi[c].y;
                ka.z += kwv * xi[c].z; ka.w += kwv * xi[c].w;
                va.x += vwv * xi[c].x; va.y += vwv * xi[c].y;
                va.z += vwv * xi[c].z; va.w += vwv * xi[c].w;
            }
            K4[base + o * HW4 + p] = ka;
            V4[base + o * HW4 + p] = va;
        }
    }

    // ---- deterministic per-wave-segment bucketing of queries by batch ----
    {
        int lane = threadIdx.x & 63;
        int W    = t >> 6;                        // segment id 0..63
        int myb  = (t < N) ? idx_b[t] : -1;
#pragma unroll
        for (int b = 0; b < Bq; ++b) {
            unsigned long long mask = __ballot(myb == b);
            if (myb == b) {
                int rank = __popcll(mask & ((1ull << lane) - 1ull));
                seg_bkt[b * NQMAX + W * 64 + rank] = t;
            }
            if (lane == 0) seg_cnt[b * 64 + W] = (int)__popcll(mask);
        }
    }
}

// ---------------------------------------------------------------------------
// Kernel B: grouped attention. One wave handles Gq=4 queries of ONE batch,
// streaming that batch's K/V once (L2 traffic /4). Wave (b,g) locates its
// queries via shuffle prefix-sum over the 64 segment counts.
// Online softmax in log2 domain (log2e folded into q); butterfly merge;
// scatter gamma*out + xi into y.
// ---------------------------------------------------------------------------
__global__ __launch_bounds__(256) void attn_grouped(
    const float* __restrict__ x,
    const float* __restrict__ qw, const float* __restrict__ qb,
    const float4* __restrict__ K4, const float4* __restrict__ V4,
    const float* __restrict__ gamma,
    const int* __restrict__ idx_h, const int* __restrict__ idx_w,
    const int* __restrict__ seg_bkt, const int* __restrict__ seg_cnt,
    float* __restrict__ y)
{
    int wave = (blockIdx.x * blockDim.x + threadIdx.x) >> 6;
    int lane = threadIdx.x & 63;
    int b    = wave >> 10;        // batch 0..3
    int g    = wave & 1023;       // group-of-4 index within batch

    // prefix-sum the 64 segment counts for this batch (lane j = segment j)
    int cnt  = seg_cnt[b * 64 + lane];
    int incl = cnt;
#pragma unroll
    for (int off = 1; off < 64; off <<= 1) {
        int u = __shfl_up(incl, off, 64);
        if (lane >= off) incl += u;
    }
    int total = __shfl(incl, 63, 64);
    if (g * Gq >= total) return;            // wave-uniform early exit
    int excl = incl - cnt;

    // locate this wave's (up to) Gq queries
    int  pos[Gq];
    bool qv[Gq];
#pragma unroll
    for (int j = 0; j < Gq; ++j) {
        int r = g * Gq + j;
        qv[j]  = (r < total);               // wave-uniform
        pos[j] = 0;
        if (qv[j]) {
            unsigned long long mk = __ballot(excl <= r && r < excl + cnt);
            int s    = __ffsll(mk) - 1;     // segment containing rank r
            int ex_s = __shfl(excl, s, 64);
            int qn   = seg_bkt[b * NQMAX + s * 64 + (r - ex_s)];
            pos[j]   = idx_h[qn] * Ww + idx_w[qn];
        }
    }

    // q vectors (log2e folded in); wave-uniform broadcast loads
    const float LOG2E = 1.4426950408889634f;
    float q2[Gq][Cc];
#pragma unroll
    for (int j = 0; j < Gq; ++j) {
        if (qv[j]) {
            float xq[Cc];
#pragma unroll
            for (int c = 0; c < Cc; ++c) xq[c] = x[b * CHW + c * HW + pos[j]];
#pragma unroll
            for (int o = 0; o < Cc; ++o) {
                float a = qb[o];
#pragma unroll
                for (int c = 0; c < Cc; ++c) a += qw[o * Cc + c] * xq[c];
                q2[j][o] = a * LOG2E;
            }
        } else {
#pragma unroll
            for (int o = 0; o < Cc; ++o) q2[j][o] = 0.f;
        }
    }

    const float4* Kb = K4 + b * (Cc * HW4);
    const float4* Vb = V4 + b * (Cc * HW4);

    float m[Gq], l[Gq], acc[Gq][Cc];
#pragma unroll
    for (int j = 0; j < Gq; ++j) {
        m[j] = -1e30f; l[j] = 0.f;
#pragma unroll
        for (int c = 0; c < Cc; ++c) acc[j][c] = 0.f;
    }

#pragma unroll 2
    for (int p = lane; p < HW4; p += 64) {   // 16 iterations
        float4 kc[Cc], vc[Cc];
#pragma unroll
        for (int c = 0; c < Cc; ++c) {
            kc[c] = Kb[c * HW4 + p];
            vc[c] = Vb[c * HW4 + p];
        }
#pragma unroll
        for (int j = 0; j < Gq; ++j) {
            float ex = q2[j][0]*kc[0].x + q2[j][1]*kc[1].x + q2[j][2]*kc[2].x
                     + q2[j][3]*kc[3].x + q2[j][4]*kc[4].x;
            float ey = q2[j][0]*kc[0].y + q2[j][1]*kc[1].y + q2[j][2]*kc[2].y
                     + q2[j][3]*kc[3].y + q2[j][4]*kc[4].y;
            float ez = q2[j][0]*kc[0].z + q2[j][1]*kc[1].z + q2[j][2]*kc[2].z
                     + q2[j][3]*kc[3].z + q2[j][4]*kc[4].z;
            float ew = q2[j][0]*kc[0].w + q2[j][1]*kc[1].w + q2[j][2]*kc[2].w
                     + q2[j][3]*kc[3].w + q2[j][4]*kc[4].w;

            float m4 = fmaxf(fmaxf(ex, ey), fmaxf(ez, ew));
            float nm = fmaxf(m[j], m4);
            float a  = fast_exp2(m[j] - nm);
            float w0 = fast_exp2(ex - nm);
            float w1 = fast_exp2(ey - nm);
            float w2 = fast_exp2(ez - nm);
            float w3 = fast_exp2(ew - nm);
            l[j] = l[j] * a + ((w0 + w1) + (w2 + w3));
#pragma unroll
            for (int c = 0; c < Cc; ++c)
                acc[j][c] = acc[j][c] * a +
                            ((w0 * vc[c].x + w1 * vc[c].y) +
                             (w2 * vc[c].z + w3 * vc[c].w));
            m[j] = nm;
        }
    }

    // butterfly merge per query (qv[j] is wave-uniform)
#pragma unroll
    for (int j = 0; j < Gq; ++j) {
        if (!qv[j]) continue;
#pragma unroll
        for (int off = 32; off >= 1; off >>= 1) {
            float m2 = __shfl_xor(m[j], off, 64);
            float l2 = __shfl_xor(l[j], off, 64);
            float nm = fmaxf(m[j], m2);
            float a  = fast_exp2(m[j] - nm);
            float a2 = fast_exp2(m2 - nm);
            l[j] = l[j] * a + l2 * a2;
#pragma unroll
            for (int c = 0; c < Cc; ++c) {
                float o2 = __shfl_xor(acc[j][c], off, 64);
                acc[j][c] = acc[j][c] * a + o2 * a2;
            }
            m[j] = nm;
        }
    }

    // scatter
#pragma unroll
    for (int j = 0; j < Gq; ++j) {
        if (qv[j] && lane < Cc) {
            int c = lane;
            float xi = x[b * CHW + c * HW + pos[j]];
            y[b * CHW + c * HW + pos[j]] = gamma[0] * (acc[j][c] / l[j]) + xi;
        }
    }
}

// ---------------------------------------------------------------------------
// Fallback (no/small workspace or oversized N): scalar inline-KV path.
// ---------------------------------------------------------------------------
__global__ void attn_scatter_inline(
    const float* __restrict__ x,
    const float* __restrict__ qw, const float* __restrict__ qb,
    const float* __restrict__ kw, const float* __restrict__ kb,
    const float* __restrict__ vw, const float* __restrict__ vb,
    const float* __restrict__ gamma,
    const int* __restrict__ idx_b, const int* __restrict__ idx_h,
    const int* __restrict__ idx_w,
    float* __restrict__ y, int N)
{
    int gtid = blockIdx.x * blockDim.x + threadIdx.x;
    int n    = gtid >> 6;
    int lane = threadIdx.x & 63;
    if (n >= N) return;

    const int b   = idx_b[n];
    const int pos = idx_h[n] * Ww + idx_w[n];

    float xq[Cc];
#pragma unroll
    for (int c = 0; c < Cc; ++c) xq[c] = x[b * CHW + c * HW + pos];
    float q[Cc];
#pragma unroll
    for (int o = 0; o < Cc; ++o) {
        float a = qb[o];
#pragma unroll
        for (int c = 0; c < Cc; ++c) a += qw[o * Cc + c] * xq[c];
        q[o] = a;
    }

    const float* Xb = x + b * CHW;
    float m = -1e30f, l = 0.f;
    float acc[Cc] = {0.f, 0.f, 0.f, 0.f, 0.f};

    for (int p = lane; p < HW; p += 64) {
        float xi[Cc];
#pragma unroll
        for (int c = 0; c < Cc; ++c) xi[c] = Xb[c * HW + p];
        float kv_k[Cc], kv_v[Cc];
#pragma unroll
        for (int o = 0; o < Cc; ++o) {
            float ka = kb[o], va = vb[o];
#pragma unroll
            for (int c = 0; c < Cc; ++c) {
                ka += kw[o * Cc + c] * xi[c];
                va += vw[o * Cc + c] * xi[c];
            }
            kv_k[o] = ka;
            kv_v[o] = va;
        }
        float e = q[0]*kv_k[0] + q[1]*kv_k[1] + q[2]*kv_k[2] + q[3]*kv_k[3] + q[4]*kv_k[4];
        float nm  = fmaxf(m, e);
        float a   = __expf(m - nm);
        float wgt = __expf(e - nm);
        l = l * a + wgt;
#pragma unroll
        for (int c = 0; c < Cc; ++c) acc[c] = acc[c] * a + wgt * kv_v[c];
        m = nm;
    }

#pragma unroll
    for (int off = 32; off >= 1; off >>= 1) {
        float m2 = __shfl_xor(m, off, 64);
        float l2 = __shfl_xor(l, off, 64);
        float nm = fmaxf(m, m2);
        float a  = __expf(m - nm);
        float a2 = __expf(m2 - nm);
        l = l * a + l2 * a2;
#pragma unroll
        for (int c = 0; c < Cc; ++c) {
            float o2 = __shfl_xor(acc[c], off, 64);
            acc[c] = acc[c] * a + o2 * a2;
        }
        m = nm;
    }

    if (lane < Cc) {
        int c = lane;
        float xi = x[b * CHW + c * HW + pos];
        y[b * CHW + c * HW + pos] = gamma[0] * (acc[c] / l) + xi;
    }
}

// ---------------------------------------------------------------------------
extern "C" void kernel_launch(void* const* d_in, const int* in_sizes, int n_in,
                              void* d_out, int out_size, void* d_ws, size_t ws_size,
                              hipStream_t stream) {
    const float* x     = (const float*)d_in[0];
    // d_in[1] = x_teature: unused by the reference
    const float* qw    = (const float*)d_in[2];
    const float* qb    = (const float*)d_in[3];
    const float* kw    = (const float*)d_in[4];
    const float* kb    = (const float*)d_in[5];
    const float* vw    = (const float*)d_in[6];
    const float* vb    = (const float*)d_in[7];
    const float* gamma = (const float*)d_in[8];
    const int*   idx_b = (const int*)d_in[9];
    const int*   idx_h = (const int*)d_in[10];
    const int*   idx_w = (const int*)d_in[11];
    const int    N     = in_sizes[9];   // idx_b element count (= index_len)

    float* y = (float*)d_out;

    // workspace layout: K | V | seg_bkt | seg_cnt
    const size_t kv_floats = (size_t)Bq * CHW;                 // per map
    const size_t need = 2 * kv_floats * sizeof(float)
                      + (size_t)(Bq * NQMAX + Bq * 64) * sizeof(int);

    if (ws_size >= need && N <= NQMAX) {
        float* K = (float*)d_ws;
        float* V = K + kv_floats;
        int* seg_bkt = (int*)(V + kv_floats);
        int* seg_cnt = seg_bkt + (size_t)Bq * NQMAX;

        prep_f4<<<(NQMAX + 255) / 256, 256, 0, stream>>>(
            (const float4*)x, kw, kb, vw, vb, idx_b, N,
            (float4*)K, (float4*)V, (float4*)y, seg_bkt, seg_cnt);

        // worst case: all N queries in one batch -> 1024 groups per batch
        const int waves  = Bq * 1024;           // 4096 waves
        const int blocks = waves * 64 / 256;    // 1024 blocks
        attn_grouped<<<blocks, 256, 0, stream>>>(
            x, qw, qb, (const float4*)K, (const float4*)V, gamma,
            idx_h, idx_w, seg_bkt, seg_cnt, y);
    } else {
        hipMemcpyAsync(y, x, (size_t)Bq * CHW * sizeof(float),
                       hipMemcpyDeviceToDevice, stream);
        const int grid_b = (N + 3) / 4;         // 4 waves per 256-thread block
        attn_scatter_inline<<<grid_b, 256, 0, stream>>>(
            x, qw, qb, kw, kb, vw, vb, gamma, idx_b, idx_h, idx_w, y, N);
    }
}

// Round 3
// 104.669 us; speedup vs baseline: 1.1865x; 1.1865x over previous
//
#include <hip/hip_runtime.h>

// Problem constants (from reference): B=4, C=5, H=64, W=64, N=4096
#define Bq  4
#define Cc  5
#define Hh  64
#define Ww  64
#define HW  (Hh * Ww)       // 4096
#define CHW (Cc * HW)       // 20480
#define HW4 (HW / 4)        // 1024 float4 per plane
#define NQMAX (Bq * HW4)    // 4096 threads in prep == max bucketable queries
#define Gq  4               // queries per workgroup in grouped attention

__device__ __forceinline__ float fast_exp2(float x) {
#if __has_builtin(__builtin_amdgcn_exp2f)
    return __builtin_amdgcn_exp2f(x);
#else
    return exp2f(x);
#endif
}

// ---------------------------------------------------------------------------
// Kernel A: K/V precompute (float4) + fused y=x copy + deterministic batch
// bucketing. 4096 threads = 64 waves; wave W compacts its 64 queries into
// per-(segment,batch) lists via ballot/popcount — no atomics, no memset.
// ---------------------------------------------------------------------------
__global__ __launch_bounds__(256) void prep_f4(
    const float4* __restrict__ x4,
    const float* __restrict__ kw, const float* __restrict__ kb,
    const float* __restrict__ vw, const float* __restrict__ vb,
    const int* __restrict__ idx_b, int N,
    float4* __restrict__ K4, float4* __restrict__ V4, float4* __restrict__ y4,
    int* __restrict__ seg_bkt,   // [Bq][64 segs][64]  = Bq*NQMAX ints
    int* __restrict__ seg_cnt)   // [Bq][64 segs]
{
    int t = blockIdx.x * blockDim.x + threadIdx.x;   // 0..4095
    if (t >= NQMAX) return;

    // ---- K/V + y=x copy ----
    {
        int b = t >> 10;            // / HW4
        int p = t & (HW4 - 1);      // % HW4
        const int base = b * (Cc * HW4);
        float4 xi[Cc];
#pragma unroll
        for (int c = 0; c < Cc; ++c) {
            xi[c] = x4[base + c * HW4 + p];
            y4[base + c * HW4 + p] = xi[c];     // fused y = x copy
        }
#pragma unroll
        for (int o = 0; o < Cc; ++o) {
            float kbo = kb[o], vbo = vb[o];
            float4 ka = {kbo, kbo, kbo, kbo};
            float4 va = {vbo, vbo, vbo, vbo};
#pragma unroll
            for (int c = 0; c < Cc; ++c) {
                float kwv = kw[o * Cc + c];
                float vwv = vw[o * Cc + c];
                ka.x += kwv * xi[c].x; ka.y += kwv * xi[c].y;
                ka.z += kwv * xi[c].z; ka.w += kwv * xi[c].w;
                va.x += vwv * xi[c].x; va.y += vwv * xi[c].y;
                va.z += vwv * xi[c].z; va.w += vwv * xi[c].w;
            }
            K4[base + o * HW4 + p] = ka;
            V4[base + o * HW4 + p] = va;
        }
    }

    // ---- deterministic per-wave-segment bucketing of queries by batch ----
    {
        int lane = threadIdx.x & 63;
        int W    = t >> 6;                        // segment id 0..63
        int myb  = (t < N) ? idx_b[t] : -1;
#pragma unroll
        for (int b = 0; b < Bq; ++b) {
            unsigned long long mask = __ballot(myb == b);
            if (myb == b) {
                int rank = __popcll(mask & ((1ull << lane) - 1ull));
                seg_bkt[b * NQMAX + W * 64 + rank] = t;
            }
            if (lane == 0) seg_cnt[b * 64 + W] = (int)__popcll(mask);
        }
    }
}

// ---------------------------------------------------------------------------
// Kernel B: grouped, key-split attention.
// One 256-thread block (4 waves) handles Gq=4 queries of ONE batch.
// Each wave processes a disjoint quarter of the 1024 float4 keys for all 4
// queries (4 iterations), reducing L2 traffic 4x vs wave-per-query while
// keeping 4096 active waves (4 waves/SIMD). Per-wave partial (m,l,acc[5])
// are merged max-first in-wave, then across the 4 waves via LDS.
// Online softmax in log2 domain (log2e folded into q).
// ---------------------------------------------------------------------------
__global__ __launch_bounds__(256) void attn_grouped_split(
    const float* __restrict__ x,
    const float* __restrict__ qw, const float* __restrict__ qb,
    const float4* __restrict__ K4, const float4* __restrict__ V4,
    const float* __restrict__ gamma,
    const int* __restrict__ idx_h, const int* __restrict__ idx_w,
    const int* __restrict__ seg_bkt, const int* __restrict__ seg_cnt,
    float* __restrict__ y)
{
    __shared__ float part[4][Gq][8];   // [wave][query][m,l,acc0..4]
    __shared__ int   spos[Gq];

    const int lane = threadIdx.x & 63;
    const int w    = threadIdx.x >> 6;     // wave 0..3 in block

    // ---- map blockIdx -> (batch b, group g) from per-batch totals ----
    // tot_b = sum over 64 segments; groups per batch = ceil(tot_b/Gq).
    int r = blockIdx.x;
    int b = -1, total = 0;
#pragma unroll
    for (int bb = 0; bb < Bq; ++bb) {
        int c = seg_cnt[bb * 64 + lane];
        int s = c;
#pragma unroll
        for (int off = 32; off >= 1; off >>= 1) s += __shfl_xor(s, off, 64);
        int gb = (s + Gq - 1) / Gq;
        if (b < 0) {
            if (r < gb) { b = bb; total = s; }
            else        { r -= gb; }
        }
    }
    if (b < 0) return;                     // uniform across whole block
    const int g = r;

    // ---- prefix-sum segment counts for batch b (lane j = segment j) ----
    int cnt  = seg_cnt[b * 64 + lane];
    int incl = cnt;
#pragma unroll
    for (int off = 1; off < 64; off <<= 1) {
        int u = __shfl_up(incl, off, 64);
        if (lane >= off) incl += u;
    }
    int excl = incl - cnt;

    // ---- locate this block's (up to) Gq queries ----
    int  pos[Gq];
    bool qv[Gq];
#pragma unroll
    for (int j = 0; j < Gq; ++j) {
        int rr = g * Gq + j;
        qv[j]  = (rr < total);             // uniform
        pos[j] = 0;
        if (qv[j]) {
            unsigned long long mk = __ballot(excl <= rr && rr < excl + cnt);
            int s    = __ffsll(mk) - 1;    // segment containing rank rr
            int ex_s = __shfl(excl, s, 64);
            int qn   = seg_bkt[b * NQMAX + s * 64 + (rr - ex_s)];
            pos[j]   = idx_h[qn] * Ww + idx_w[qn];
        }
        if (threadIdx.x == 0) spos[j] = pos[j];   // static index j
    }

    // ---- q vectors (log2e folded in); uniform broadcast loads ----
    const float LOG2E = 1.4426950408889634f;
    float q2[Gq][Cc];
#pragma unroll
    for (int j = 0; j < Gq; ++j) {
        if (qv[j]) {
            float xq[Cc];
#pragma unroll
            for (int c = 0; c < Cc; ++c) xq[c] = x[b * CHW + c * HW + pos[j]];
#pragma unroll
            for (int o = 0; o < Cc; ++o) {
                float a = qb[o];
#pragma unroll
                for (int c = 0; c < Cc; ++c) a += qw[o * Cc + c] * xq[c];
                q2[j][o] = a * LOG2E;
            }
        } else {
#pragma unroll
            for (int o = 0; o < Cc; ++o) q2[j][o] = 0.f;
        }
    }

    const float4* Kb = K4 + b * (Cc * HW4);
    const float4* Vb = V4 + b * (Cc * HW4);

    float m[Gq], l[Gq], acc[Gq][Cc];
#pragma unroll
    for (int j = 0; j < Gq; ++j) {
        m[j] = -1e30f; l[j] = 0.f;
#pragma unroll
        for (int c = 0; c < Cc; ++c) acc[j][c] = 0.f;
    }

    // ---- main loop: this wave's quarter of the keys (4 iterations) ----
    const int p0 = w * (HW4 / 4) + lane;
#pragma unroll 2
    for (int it = 0; it < (HW4 / 4) / 64; ++it) {   // 4 iterations
        int p = p0 + it * 64;
        float4 kc[Cc], vc[Cc];
#pragma unroll
        for (int c = 0; c < Cc; ++c) {
            kc[c] = Kb[c * HW4 + p];
            vc[c] = Vb[c * HW4 + p];
        }
#pragma unroll
        for (int j = 0; j < Gq; ++j) {
            float ex = q2[j][0]*kc[0].x + q2[j][1]*kc[1].x + q2[j][2]*kc[2].x
                     + q2[j][3]*kc[3].x + q2[j][4]*kc[4].x;
            float ey = q2[j][0]*kc[0].y + q2[j][1]*kc[1].y + q2[j][2]*kc[2].y
                     + q2[j][3]*kc[3].y + q2[j][4]*kc[4].y;
            float ez = q2[j][0]*kc[0].z + q2[j][1]*kc[1].z + q2[j][2]*kc[2].z
                     + q2[j][3]*kc[3].z + q2[j][4]*kc[4].z;
            float ew = q2[j][0]*kc[0].w + q2[j][1]*kc[1].w + q2[j][2]*kc[2].w
                     + q2[j][3]*kc[3].w + q2[j][4]*kc[4].w;

            float m4 = fmaxf(fmaxf(ex, ey), fmaxf(ez, ew));
            float nm = fmaxf(m[j], m4);
            float a  = fast_exp2(m[j] - nm);
            float w0 = fast_exp2(ex - nm);
            float w1 = fast_exp2(ey - nm);
            float w2 = fast_exp2(ez - nm);
            float w3 = fast_exp2(ew - nm);
            l[j] = l[j] * a + ((w0 + w1) + (w2 + w3));
#pragma unroll
            for (int c = 0; c < Cc; ++c)
                acc[j][c] = acc[j][c] * a +
                            ((w0 * vc[c].x + w1 * vc[c].y) +
                             (w2 * vc[c].z + w3 * vc[c].w));
            m[j] = nm;
        }
    }

    // ---- in-wave reduce (max-first: 1 exp + plain-sum butterflies) ----
#pragma unroll
    for (int j = 0; j < Gq; ++j) {
        float mm = m[j];
#pragma unroll
        for (int off = 32; off >= 1; off >>= 1)
            mm = fmaxf(mm, __shfl_xor(mm, off, 64));
        float a  = fast_exp2(m[j] - mm);
        float ll = l[j] * a;
        float ac[Cc];
#pragma unroll
        for (int c = 0; c < Cc; ++c) ac[c] = acc[j][c] * a;
#pragma unroll
        for (int off = 32; off >= 1; off >>= 1) {
            ll += __shfl_xor(ll, off, 64);
#pragma unroll
            for (int c = 0; c < Cc; ++c) ac[c] += __shfl_xor(ac[c], off, 64);
        }
        if (lane == 0) {
            part[w][j][0] = mm;
            part[w][j][1] = ll;
#pragma unroll
            for (int c = 0; c < Cc; ++c) part[w][j][2 + c] = ac[c];
        }
    }
    __syncthreads();

    // ---- cross-wave combine + scatter: one thread per (query, channel) ----
    const int tid = threadIdx.x;
    if (tid < Gq * Cc) {
        int j = tid / Cc, c = tid % Cc;
        if (g * Gq + j < total) {
            float m0 = part[0][j][0], m1 = part[1][j][0];
            float m2 = part[2][j][0], m3 = part[3][j][0];
            float mmax = fmaxf(fmaxf(m0, m1), fmaxf(m2, m3));
            float a0 = fast_exp2(m0 - mmax), a1 = fast_exp2(m1 - mmax);
            float a2 = fast_exp2(m2 - mmax), a3 = fast_exp2(m3 - mmax);
            float lsum = part[0][j][1]*a0 + part[1][j][1]*a1
                       + part[2][j][1]*a2 + part[3][j][1]*a3;
            float asum = part[0][j][2+c]*a0 + part[1][j][2+c]*a1
                       + part[2][j][2+c]*a2 + part[3][j][2+c]*a3;
            int   pp = spos[j];
            float xi = x[b * CHW + c * HW + pp];
            y[b * CHW + c * HW + pp] = gamma[0] * (asum / lsum) + xi;
        }
    }
}

// ---------------------------------------------------------------------------
// Fallback (no/small workspace or oversized N): scalar inline-KV path.
// ---------------------------------------------------------------------------
__global__ void attn_scatter_inline(
    const float* __restrict__ x,
    const float* __restrict__ qw, const float* __restrict__ qb,
    const float* __restrict__ kw, const float* __restrict__ kb,
    const float* __restrict__ vw, const float* __restrict__ vb,
    const float* __restrict__ gamma,
    const int* __restrict__ idx_b, const int* __restrict__ idx_h,
    const int* __restrict__ idx_w,
    float* __restrict__ y, int N)
{
    int gtid = blockIdx.x * blockDim.x + threadIdx.x;
    int n    = gtid >> 6;
    int lane = threadIdx.x & 63;
    if (n >= N) return;

    const int b   = idx_b[n];
    const int pos = idx_h[n] * Ww + idx_w[n];

    float xq[Cc];
#pragma unroll
    for (int c = 0; c < Cc; ++c) xq[c] = x[b * CHW + c * HW + pos];
    float q[Cc];
#pragma unroll
    for (int o = 0; o < Cc; ++o) {
        float a = qb[o];
#pragma unroll
        for (int c = 0; c < Cc; ++c) a += qw[o * Cc + c] * xq[c];
        q[o] = a;
    }

    const float* Xb = x + b * CHW;
    float m = -1e30f, l = 0.f;
    float acc[Cc] = {0.f, 0.f, 0.f, 0.f, 0.f};

    for (int p = lane; p < HW; p += 64) {
        float xi[Cc];
#pragma unroll
        for (int c = 0; c < Cc; ++c) xi[c] = Xb[c * HW + p];
        float kv_k[Cc], kv_v[Cc];
#pragma unroll
        for (int o = 0; o < Cc; ++o) {
            float ka = kb[o], va = vb[o];
#pragma unroll
            for (int c = 0; c < Cc; ++c) {
                ka += kw[o * Cc + c] * xi[c];
                va += vw[o * Cc + c] * xi[c];
            }
            kv_k[o] = ka;
            kv_v[o] = va;
        }
        float e = q[0]*kv_k[0] + q[1]*kv_k[1] + q[2]*kv_k[2] + q[3]*kv_k[3] + q[4]*kv_k[4];
        float nm  = fmaxf(m, e);
        float a   = __expf(m - nm);
        float wgt = __expf(e - nm);
        l = l * a + wgt;
#pragma unroll
        for (int c = 0; c < Cc; ++c) acc[c] = acc[c] * a + wgt * kv_v[c];
        m = nm;
    }

#pragma unroll
    for (int off = 32; off >= 1; off >>= 1) {
        float m2 = __shfl_xor(m, off, 64);
        float l2 = __shfl_xor(l, off, 64);
        float nm = fmaxf(m, m2);
        float a  = __expf(m - nm);
        float a2 = __expf(m2 - nm);
        l = l * a + l2 * a2;
#pragma unroll
        for (int c = 0; c < Cc; ++c) {
            float o2 = __shfl_xor(acc[c], off, 64);
            acc[c] = acc[c] * a + o2 * a2;
        }
        m = nm;
    }

    if (lane < Cc) {
        int c = lane;
        float xi = x[b * CHW + c * HW + pos];
        y[b * CHW + c * HW + pos] = gamma[0] * (acc[c] / l) + xi;
    }
}

// ---------------------------------------------------------------------------
extern "C" void kernel_launch(void* const* d_in, const int* in_sizes, int n_in,
                              void* d_out, int out_size, void* d_ws, size_t ws_size,
                              hipStream_t stream) {
    const float* x     = (const float*)d_in[0];
    // d_in[1] = x_teature: unused by the reference
    const float* qw    = (const float*)d_in[2];
    const float* qb    = (const float*)d_in[3];
    const float* kw    = (const float*)d_in[4];
    const float* kb    = (const float*)d_in[5];
    const float* vw    = (const float*)d_in[6];
    const float* vb    = (const float*)d_in[7];
    const float* gamma = (const float*)d_in[8];
    const int*   idx_b = (const int*)d_in[9];
    const int*   idx_h = (const int*)d_in[10];
    const int*   idx_w = (const int*)d_in[11];
    const int    N     = in_sizes[9];   // idx_b element count (= index_len)

    float* y = (float*)d_out;

    // workspace layout: K | V | seg_bkt | seg_cnt
    const size_t kv_floats = (size_t)Bq * CHW;                 // per map
    const size_t need = 2 * kv_floats * sizeof(float)
                      + (size_t)(Bq * NQMAX + Bq * 64) * sizeof(int);

    if (ws_size >= need && N <= NQMAX) {
        float* K = (float*)d_ws;
        float* V = K + kv_floats;
        int* seg_bkt = (int*)(V + kv_floats);
        int* seg_cnt = seg_bkt + (size_t)Bq * NQMAX;

        prep_f4<<<(NQMAX + 255) / 256, 256, 0, stream>>>(
            (const float4*)x, kw, kb, vw, vb, idx_b, N,
            (float4*)K, (float4*)V, (float4*)y, seg_bkt, seg_cnt);

        // one block per group of Gq queries; +Bq-1 covers per-batch ceil slack
        const int blocks = (N + Gq - 1) / Gq + (Bq - 1);
        attn_grouped_split<<<blocks, 256, 0, stream>>>(
            x, qw, qb, (const float4*)K, (const float4*)V, gamma,
            idx_h, idx_w, seg_bkt, seg_cnt, y);
    } else {
        hipMemcpyAsync(y, x, (size_t)Bq * CHW * sizeof(float),
                       hipMemcpyDeviceToDevice, stream);
        const int grid_b = (N + 3) / 4;         // 4 waves per 256-thread block
        attn_scatter_inline<<<grid_b, 256, 0, stream>>>(
            x, qw, qb, kw, kb, vw, vb, gamma, idx_b, idx_h, idx_w, y, N);
    }
}